// Round 16
// baseline (56.139 us; speedup 1.0000x reference)
//
#include <hip/hip_runtime.h>
#include <cstddef>

#define BB  32
#define CC  128
#define HH  64
#define WW  64
#define OO  256
#define OHH 32
#define OWW 32
#define YSTR 196              // yr c-row stride (3*64 + 4 pad), 392B
#define PROW (32 * YSTR)      // 6272: one p-row (32 c-rows)
#define YRHALF (2 * PROW)     // 12544: one p-pair buffer
#define PSTR 296              // pT row stride, 592B (16B-aligned)
#define PTHALF (64 * PSTR)    // 18944: one n-half buffer

typedef __bf16 bf16x8 __attribute__((ext_vector_type(8)));
typedef __bf16 bf16x4 __attribute__((ext_vector_type(4)));
typedef float  f32x4  __attribute__((ext_vector_type(4)));

// ---- weight transform: w[o][c][3][3] f32 -> wt[o][k][c] bf16 (k = kh*3+kw) ----
__global__ void wtrans_bf16_kernel(const float* __restrict__ w, __bf16* __restrict__ wt) {
    int idx = blockIdx.x * 256 + threadIdx.x;          // (o*9 + k)*128 + c
    if (idx >= OO * 9 * CC) return;
    int c    = idx & 127;
    int rest = idx >> 7;
    int k    = rest % 9;
    int o    = rest / 9;
    wt[idx] = (__bf16)w[((size_t)o * CC + c) * 9 + k];
}

// ---- fused bilinear-im2col + bf16 MFMA; block = (b, 4 p-rows), N=128 ----
// R16 = R15 with the PIN macro fixed (scalar components; float4 "v" operands
// don't compile). 3-stage pipeline at half granularity: yr split by p-pair
// (2x25KB), pT split by n-half (2x37.9KB) -> 126KB LDS, both double-buffered.
// Each phase: A(issue x, finish after MFMA) || B(build next pT half) || M(MFMA).
__global__ __launch_bounds__(512, 2)
void conv_mfma_kernel(const float* __restrict__ x, const __bf16* __restrict__ wt,
                      const float* __restrict__ bias, const float* __restrict__ shp,
                      const float* __restrict__ swp, float* __restrict__ out) {
    __shared__ __align__(16) __bf16 yrbuf[8 + 2 * YRHALF + 8];  // front pad 8
    __shared__ __align__(16) __bf16 pT[2 * PTHALF];

    const int tid = threadIdx.x;
    const int b   = blockIdx.x;
    const int p0  = blockIdx.y * 4;
    const float sh = shp[0];
    const float sw = swp[0];

    float fh_[4];
    int   hb_[4];
    bool  oob[4];
#pragma unroll
    for (int pi = 0; pi < 4; ++pi) {
        float hpos = (float)(p0 + pi) * sh - 1.0f;
        float hbf  = floorf(hpos);
        fh_[pi] = hpos - hbf;
        hb_[pi] = (int)hbf;
        oob[pi] = (hb_[pi] >= HH || hb_[pi] <= -4);
    }

    // ---- bias-only fast path: all 4 rows fully OOB ----
    if (oob[0] && oob[1] && oob[2] && oob[3]) {
#pragma unroll
        for (int j = 0; j < 16; ++j) {
            int fi = j * 512 + tid;
            int o  = fi >> 5;
            int rem = fi & 31;
            int pi = rem >> 3;
            int qf = rem & 7;
            float bv = bias[o];
            float4 r; r.x = bv; r.y = bv; r.z = bv; r.w = bv;
            *(float4*)(out + (((size_t)b * OO + o) * OHH + p0 + pi) * OWW + qf * 4) = r;
        }
        return;
    }

    // ---- stage-A ownership: (pi2 within pair, c, 8-col group) ----
    const int pi2A = tid >> 8;            // 0..1
    const int cA   = (tid >> 3) & 31;     // 0..31
    const int colg = (tid & 7) * 8;       // 0..56
    int  hr4[4][4];
    bool rv4[4][4];
#pragma unroll
    for (int pi = 0; pi < 4; ++pi)
#pragma unroll
        for (int r = 0; r < 4; ++r) {
            hr4[pi][r] = hb_[pi] + r;
            rv4[pi][r] = (hr4[pi][r] >= 0) && (hr4[pi][r] < HH);
        }

    // ---- stage-B ownership: (n-row within half, 4-channel group) ----
    const int qB2  = tid >> 3;            // 0..63 = n-row within half
    const int pi2B = qB2 >> 5;            // 0..1
    const int qB   = qB2 & 31;
    const int cg0  = (tid & 7) * 4;       // 0..28
    const float wposB = (float)qB * sw - 1.0f;
    const float wbfB  = floorf(wposB);
    const float fw    = wposB - wbfB;
    const int   wbq   = (int)wbfB;
    const int   wba   = min(wbq & ~3, 60);
    const int   e     = wbq - wba;
    const bool  g1 = e >= 1, g2 = e >= 2, g3 = e >= 3;
    bool mv[4];
#pragma unroll
    for (int j = 0; j < 4; ++j) mv[j] = ((unsigned)(wbq + j) < (unsigned)WW);

    // ---- MFMA ownership: wave -> 32 o; per phase one n-half (64 n) ----
    const int wv = tid >> 6;
    const int l  = tid & 63;
    const int lr = l & 15;
    const int lg = l >> 4;
    const int o0 = wv * 32;

    f32x4 acc[2][8];
#pragma unroll
    for (int ot = 0; ot < 2; ++ot)
#pragma unroll
        for (int nt = 0; nt < 8; ++nt) acc[ot][nt] = (f32x4)0.0f;

    if (tid < 8) yrbuf[tid] = (__bf16)0.0f;   // zero front pad

    float4 vx[2][4];     // x prefetch: [col4-group][row]
    bf16x8 wa[9][2];     // wt fragments held across a chunk's two phases

    // ---- A: issue x loads for (chunk c0, pair P) ----
    auto aIssue = [&](int c0, int P) {
        const int p = P * 2 + pi2A;
        const float* xp = x + ((size_t)(b * CC + c0 + cA) * HH) * WW + colg;
#pragma unroll
        for (int r = 0; r < 4; ++r) {
            float4 t0 = {0.f, 0.f, 0.f, 0.f}, t1 = t0;
            if (rv4[p][r]) {
                const float* rp = xp + (size_t)hr4[p][r] * WW;
                t0 = *(const float4*)(rp);
                t1 = *(const float4*)(rp + 4);
            }
            vx[0][r] = t0;
            vx[1][r] = t1;
        }
    };

    // ---- A: row-interp + write yr[P] (consumes vx) ----
    auto aFinish = [&](int P) {
        const int p = P * 2 + pi2A;
        const float fh = fh_[p];
        __bf16* yw = yrbuf + 8 + P * YRHALF + pi2A * PROW + cA * YSTR + colg;
#pragma unroll
        for (int kh = 0; kh < 3; ++kh) {
#pragma unroll
            for (int h = 0; h < 2; ++h) {
                float4 a = vx[h][kh], d = vx[h][kh + 1];
                bf16x4 t;
                t[0] = (__bf16)(a.x + fh * (d.x - a.x));
                t[1] = (__bf16)(a.y + fh * (d.y - a.y));
                t[2] = (__bf16)(a.z + fh * (d.z - a.z));
                t[3] = (__bf16)(a.w + fh * (d.w - a.w));
                *(bf16x4*)(yw + kh * 64 + h * 4) = t;
            }
        }
    };

    // ---- B: col-interp yr[P] -> pT[P] ----
    auto doB = [&](int P) {
        const __bf16* ybase = yrbuf + 8 + P * YRHALF + pi2B * PROW;
        __bf16* pq = pT + P * PTHALF + qB2 * PSTR;
        float tv[3][3][4];   // [kh][kw][ci]
#pragma unroll
        for (int ci = 0; ci < 4; ++ci) {
            const __bf16* yc = ybase + (cg0 + ci) * YSTR + wba;
#pragma unroll
            for (int kh = 0; kh < 3; ++kh) {
                bf16x4 a  = *(const bf16x4*)(yc + kh * 64);
                bf16x4 bq = *(const bf16x4*)(yc + kh * 64 + 4);
                float v0 = (float)a[0], v1 = (float)a[1], v2 = (float)a[2], v3 = (float)a[3];
                float v4 = (float)bq[0], v5 = (float)bq[1], v6 = (float)bq[2];
                float s0 = g1 ? v1 : v0; s0 = g2 ? v2 : s0; s0 = g3 ? v3 : s0;
                float s1 = g1 ? v2 : v1; s1 = g2 ? v3 : s1; s1 = g3 ? v4 : s1;
                float s2 = g1 ? v3 : v2; s2 = g2 ? v4 : s2; s2 = g3 ? v5 : s2;
                float s3 = g1 ? v4 : v3; s3 = g2 ? v5 : s3; s3 = g3 ? v6 : s3;
                s0 = mv[0] ? s0 : 0.0f;
                s1 = mv[1] ? s1 : 0.0f;
                s2 = mv[2] ? s2 : 0.0f;
                s3 = mv[3] ? s3 : 0.0f;
                tv[kh][0][ci] = s0 + fw * (s1 - s0);
                tv[kh][1][ci] = s1 + fw * (s2 - s1);
                tv[kh][2][ci] = s2 + fw * (s3 - s2);
            }
        }
#pragma unroll
        for (int kh = 0; kh < 3; ++kh)
#pragma unroll
            for (int kw = 0; kw < 3; ++kw) {
                bf16x4 pr;
                pr[0] = (__bf16)tv[kh][kw][0];
                pr[1] = (__bf16)tv[kh][kw][1];
                pr[2] = (__bf16)tv[kh][kw][2];
                pr[3] = (__bf16)tv[kh][kw][3];
                *(bf16x4*)(pq + (kh * 3 + kw) * 32 + cg0) = pr;
            }
    };

    // ---- M: 9 taps x (2 ot x 4 nt) on pT[nh]; A frags loaded on nh==0 ----
    auto doM = [&](int c0, int nh, bool loadA) {
        __builtin_amdgcn_s_setprio(1);
#pragma unroll
        for (int k = 0; k < 9; ++k) {
            if (loadA) {
                const __bf16* wp = wt + ((size_t)(o0 + lr) * 9 + k) * CC + c0 + lg * 8;
                wa[k][0] = *(const bf16x8*)(wp);
                wa[k][1] = *(const bf16x8*)(wp + (size_t)16 * 9 * CC);
            }
            const __bf16* pb = pT + nh * PTHALF + lr * PSTR + k * 32 + lg * 8;
            bf16x8 b0 = *(const bf16x8*)(pb);
            bf16x8 b1 = *(const bf16x8*)(pb + 16 * PSTR);
            bf16x8 b2 = *(const bf16x8*)(pb + 32 * PSTR);
            bf16x8 b3 = *(const bf16x8*)(pb + 48 * PSTR);
            acc[0][nh * 4 + 0] = __builtin_amdgcn_mfma_f32_16x16x32_bf16(wa[k][0], b0, acc[0][nh * 4 + 0], 0, 0, 0);
            acc[0][nh * 4 + 1] = __builtin_amdgcn_mfma_f32_16x16x32_bf16(wa[k][0], b1, acc[0][nh * 4 + 1], 0, 0, 0);
            acc[0][nh * 4 + 2] = __builtin_amdgcn_mfma_f32_16x16x32_bf16(wa[k][0], b2, acc[0][nh * 4 + 2], 0, 0, 0);
            acc[0][nh * 4 + 3] = __builtin_amdgcn_mfma_f32_16x16x32_bf16(wa[k][0], b3, acc[0][nh * 4 + 3], 0, 0, 0);
            acc[1][nh * 4 + 0] = __builtin_amdgcn_mfma_f32_16x16x32_bf16(wa[k][1], b0, acc[1][nh * 4 + 0], 0, 0, 0);
            acc[1][nh * 4 + 1] = __builtin_amdgcn_mfma_f32_16x16x32_bf16(wa[k][1], b1, acc[1][nh * 4 + 1], 0, 0, 0);
            acc[1][nh * 4 + 2] = __builtin_amdgcn_mfma_f32_16x16x32_bf16(wa[k][1], b2, acc[1][nh * 4 + 2], 0, 0, 0);
            acc[1][nh * 4 + 3] = __builtin_amdgcn_mfma_f32_16x16x32_bf16(wa[k][1], b3, acc[1][nh * 4 + 3], 0, 0, 0);
        }
        __builtin_amdgcn_s_setprio(0);
    };

    // pin vx via scalar components: one component per dwordx4 load forces the
    // whole load issued before this point (float4 "v" operands don't compile).
#define PIN_VX() asm volatile("" :: \
    "v"(vx[0][0].x), "v"(vx[0][1].x), "v"(vx[0][2].x), "v"(vx[0][3].x), \
    "v"(vx[1][0].x), "v"(vx[1][1].x), "v"(vx[1][2].x), "v"(vx[1][3].x))

    // ---- pipeline prologue ----
    aIssue(0, 0); aFinish(0);
    __syncthreads();
    aIssue(0, 1); doB(0); aFinish(1);
    __syncthreads();

    // ---- steady state: chunks 0..2, two phases each ----
#pragma unroll
    for (int c = 0; c < 3; ++c) {
        // even phase: M(c,0) || B(c,1) || A(c+1, pair0)
        aIssue((c + 1) * 32, 0);
        doB(1);
        PIN_VX();
        doM(c * 32, 0, true);
        aFinish(0);
        __syncthreads();
        // odd phase: M(c,1) || B(c+1,0) || A(c+1, pair1)
        aIssue((c + 1) * 32, 1);
        doB(0);
        PIN_VX();
        doM(c * 32, 1, false);
        aFinish(1);
        __syncthreads();
    }
    // ---- tail: chunk 3 ----
    doB(1);
    doM(96, 0, true);
    __syncthreads();
    doM(96, 1, false);
#undef PIN_VX

    // ---- epilogue: + bias, store (C/D: col=lane&15, row=(lane>>4)*4+reg) ----
#pragma unroll
    for (int ot = 0; ot < 2; ++ot) {
#pragma unroll
        for (int r = 0; r < 4; ++r) {
            int o = o0 + ot * 16 + lg * 4 + r;
            float bv = bias[o];
#pragma unroll
            for (int nt = 0; nt < 8; ++nt) {
                int pi = nt >> 1;
                int qc = (nt & 1) * 16 + lr;
                out[(((size_t)b * OO + o) * OHH + p0 + pi) * OWW + qc] = acc[ot][nt][r] + bv;
            }
        }
    }
}

// ---- fp32 fallback (no workspace) ----
__global__ __launch_bounds__(256)
void conv_fallback_kernel(const float* __restrict__ x, const float* __restrict__ w,
                          const float* __restrict__ bias, const float* __restrict__ shp,
                          const float* __restrict__ swp, float* __restrict__ out) {
    __shared__ __align__(16) float xr[4][WW];
    __shared__ __align__(16) float patch[9][OWW];
    const int tid = threadIdx.x;
    const int p = blockIdx.y;
    const int b = blockIdx.x;
    const float sh = shp[0];
    const float sw = swp[0];
    const float hpos = (float)p * sh - 1.0f;
    const float hbf  = floorf(hpos);
    const float fh   = hpos - hbf;
    const int   hb   = (int)hbf;
    const int og = tid & 63;
    const int qg = tid >> 6;
    const int o0 = og * 4;
    const int q0 = qg * 8;
    const int rr   = tid >> 6;
    const int colc = tid & 63;
    const int rowg = hb + rr;
    const bool rv = (rowg >= 0) && (rowg < HH);
    float acc[4][8];
#pragma unroll
    for (int i = 0; i < 4; ++i)
#pragma unroll
        for (int j = 0; j < 8; ++j) acc[i][j] = 0.0f;
    for (int c = 0; c < CC; ++c) {
        float vv = 0.0f;
        if (rv) vv = x[(((size_t)b * CC + c) * HH + rowg) * WW + colc];
        xr[rr][colc] = vv;
        __syncthreads();
        for (int it = tid; it < 9 * OWW; it += 256) {
            int k = it >> 5; int q = it & 31;
            int kh = k / 3;  int kw = k - kh * 3;
            float wpos = (float)q * sw - 1.0f + (float)kw;
            float wbf = floorf(wpos);
            float fwl = wpos - wbf;
            int wb = (int)wbf;
            float x00 = 0, x01 = 0, x10 = 0, x11 = 0;
            if (wb >= 0 && wb < WW)         { x00 = xr[kh][wb];     x10 = xr[kh + 1][wb]; }
            if (wb + 1 >= 0 && wb + 1 < WW) { x01 = xr[kh][wb + 1]; x11 = xr[kh + 1][wb + 1]; }
            float top = x00 * (1.0f - fwl) + x01 * fwl;
            float bot = x10 * (1.0f - fwl) + x11 * fwl;
            patch[k][q] = top * (1.0f - fh) + bot * fh;
        }
        __syncthreads();
        const float4* pv = (const float4*)&patch[0][0];
#pragma unroll
        for (int k = 0; k < 9; ++k) {
            const float* wb_ = w + (size_t)o0 * (CC * 9) + c * 9 + k;
            float wvv[4] = {wb_[0], wb_[1 * CC * 9], wb_[2 * CC * 9], wb_[3 * CC * 9]};
            float4 pa = pv[k * 8 + (q0 >> 2)];
            float4 pb = pv[k * 8 + (q0 >> 2) + 1];
#pragma unroll
            for (int oo2 = 0; oo2 < 4; ++oo2) {
                acc[oo2][0] += wvv[oo2] * pa.x; acc[oo2][1] += wvv[oo2] * pa.y;
                acc[oo2][2] += wvv[oo2] * pa.z; acc[oo2][3] += wvv[oo2] * pa.w;
                acc[oo2][4] += wvv[oo2] * pb.x; acc[oo2][5] += wvv[oo2] * pb.y;
                acc[oo2][6] += wvv[oo2] * pb.z; acc[oo2][7] += wvv[oo2] * pb.w;
            }
        }
    }
    float4 bv = ((const float4*)bias)[og];
    float bvv[4] = {bv.x, bv.y, bv.z, bv.w};
#pragma unroll
    for (int oo2 = 0; oo2 < 4; ++oo2) {
        size_t off = (((size_t)b * OO + o0 + oo2) * OHH + p) * OWW + q0;
        float4 r0, r1;
        r0.x = acc[oo2][0] + bvv[oo2]; r0.y = acc[oo2][1] + bvv[oo2];
        r0.z = acc[oo2][2] + bvv[oo2]; r0.w = acc[oo2][3] + bvv[oo2];
        r1.x = acc[oo2][4] + bvv[oo2]; r1.y = acc[oo2][5] + bvv[oo2];
        r1.z = acc[oo2][6] + bvv[oo2]; r1.w = acc[oo2][7] + bvv[oo2];
        *(float4*)(out + off)     = r0;
        *(float4*)(out + off + 4) = r1;
    }
}

extern "C" void kernel_launch(void* const* d_in, const int* in_sizes, int n_in,
                              void* d_out, int out_size, void* d_ws, size_t ws_size,
                              hipStream_t stream) {
    const float* x    = (const float*)d_in[0];
    const float* w    = (const float*)d_in[1];
    const float* bias = (const float*)d_in[2];
    const float* shp  = (const float*)d_in[3];
    const float* swp  = (const float*)d_in[4];
    float* out = (float*)d_out;

    const size_t wt_bytes = (size_t)OO * 9 * CC * sizeof(__bf16);   // 576 KB
    if (ws_size >= wt_bytes) {
        __bf16* wtp = (__bf16*)d_ws;
        int n = OO * 9 * CC;
        wtrans_bf16_kernel<<<(n + 255) / 256, 256, 0, stream>>>(w, wtp);
        dim3 grid(BB, OHH / 4);
        conv_mfma_kernel<<<grid, 512, 0, stream>>>(x, wtp, bias, shp, swp, out);
    } else {
        dim3 grid(BB, OHH);
        conv_fallback_kernel<<<grid, 256, 0, stream>>>(x, w, bias, shp, swp, out);
    }
}

// Round 17
// 55.300 us; speedup vs baseline: 1.0152x; 1.0152x over previous
//
#include <hip/hip_runtime.h>
#include <cstddef>

#define BB  32
#define CC  128
#define HH  64
#define WW  64
#define OO  256
#define OHH 32
#define OWW 32
#define YSTR 196            // yr row stride (bf16 elems)
#define PSTR 296            // pT row stride; 592B rows, 16B-aligned
#define ROWE (32 * YSTR)    // 6272 elems per yr(p) buffer

typedef __bf16 bf16x8 __attribute__((ext_vector_type(8)));
typedef __bf16 bf16x4 __attribute__((ext_vector_type(4)));
typedef float  f32x4  __attribute__((ext_vector_type(4)));

// ---- weight transform: w[o][c][3][3] f32 -> wt[o][k][c] bf16 (k = kh*3+kw) ----
__global__ void wtrans_bf16_kernel(const float* __restrict__ w, __bf16* __restrict__ wt) {
    int idx = blockIdx.x * 256 + threadIdx.x;          // (o*9 + k)*128 + c
    if (idx >= OO * 9 * CC) return;
    int c    = idx & 127;
    int rest = idx >> 7;
    int k    = rest % 9;
    int o    = rest / 9;
    wt[idx] = (__bf16)w[((size_t)o * CC + c) * 9 + k];
}

// ---- fused bilinear-im2col + bf16 MFMA; block = (b, 4 p-rows), N=128 ----
// R17 = R14 (55.1us winner) + (1) stage-B LDS reads hoisted per group (24 b64
// in flight covers ~120cy LDS latency at 2 waves/SIMD) + (2) dead-q skip:
// q>=26 columns are provably zero (wbq>=64 -> all taps masked) -> zero those
// pT rows once, skip their stage-B work every chunk.
__global__ __launch_bounds__(512, 2)
void conv_mfma_kernel(const float* __restrict__ x, const __bf16* __restrict__ wt,
                      const float* __restrict__ bias, const float* __restrict__ shp,
                      const float* __restrict__ swp, float* __restrict__ out) {
    __shared__ __align__(16) __bf16 yrbuf[4 + 4 * ROWE];   // 4 p-rows + front pad
    __shared__ __align__(16) __bf16 pT[128 * PSTR];        // B operand: row = pi*32+q

    const int tid = threadIdx.x;
    const int b   = blockIdx.x;
    const int p0  = blockIdx.y * 4;
    const float sh = shp[0];
    const float sw = swp[0];

    // per-p row geometry (4 rows of this block)
    float fh_[4];
    int   hb_[4];
    bool  oob[4];
#pragma unroll
    for (int pi = 0; pi < 4; ++pi) {
        float hpos = (float)(p0 + pi) * sh - 1.0f;
        float hbf  = floorf(hpos);
        fh_[pi] = hpos - hbf;
        hb_[pi] = (int)hbf;
        oob[pi] = (hb_[pi] >= HH || hb_[pi] <= -4);
    }

    // ---- bias-only fast path: all 4 rows fully OOB ----
    if (oob[0] && oob[1] && oob[2] && oob[3]) {
#pragma unroll
        for (int j = 0; j < 16; ++j) {
            int fi = j * 512 + tid;        // 8192 float4 = 256 o x 4 p x 8
            int o  = fi >> 5;
            int rem = fi & 31;
            int pi = rem >> 3;
            int qf = rem & 7;
            float bv = bias[o];
            float4 r; r.x = bv; r.y = bv; r.z = bv; r.w = bv;
            *(float4*)(out + (((size_t)b * OO + o) * OHH + p0 + pi) * OWW + qf * 4) = r;
        }
        return;
    }
    // (mixed OOB rows fall through: masked loads -> zero patch -> bias)

    // ---- stage-A ownership: 128 threads per p-row; (c, 16-col group) ----
    const int piA = tid >> 7;             // 0..3
    const int t7  = tid & 127;
    const int cA  = t7 >> 2;              // 0..31
    const int cg0 = (t7 & 3) * 16;        // col group start: 0,16,32,48
    const float fhA = fh_[piA];
    int  hrA[4];
    bool rvA[4];
#pragma unroll
    for (int r = 0; r < 4; ++r) {
        hrA[r] = hb_[piA] + r;
        rvA[r] = (hrA[r] >= 0) && (hrA[r] < HH);
    }
    __bf16* yrA = yrbuf + 4 + piA * ROWE;

    // ---- stage-B ownership: (pi, q, 8 channels in 2 groups of 4) ----
    const int piB = tid >> 7;             // 0..3
    const int qB  = (tid >> 2) & 31;      // 0..31
    const int cB  = (tid & 3) * 8;        // 0,8,16,24
    const float wposB = (float)qB * sw - 1.0f;
    const float wbfB  = floorf(wposB);
    const float fw    = wposB - wbfB;
    const int   wbq   = (int)wbfB;
    const int   wba   = min(wbq & ~3, 60);
    const int   e     = wbq - wba;
    const bool  g1 = e >= 1, g2 = e >= 2, g3 = e >= 3;
    bool mv[4];
#pragma unroll
    for (int j = 0; j < 4; ++j) mv[j] = ((unsigned)(wbq + j) < (unsigned)WW);
    const bool qDead = (wbq >= WW);       // q>=26: every tap right-OOB -> patch==0
    const __bf16* yrB = yrbuf + 4 + piB * ROWE;
    __bf16* pqRow = pT + (piB * 32 + qB) * PSTR;

    // ---- MFMA ownership: wave -> 32 o; all 128 n-rows ----
    const int wv = tid >> 6;
    const int l  = tid & 63;
    const int lr = l & 15;
    const int lg = l >> 4;
    const int o0 = wv * 32;

    f32x4 acc[2][8];
#pragma unroll
    for (int ot = 0; ot < 2; ++ot)
#pragma unroll
        for (int nt = 0; nt < 8; ++nt) acc[ot][nt] = (f32x4)0.0f;

    if (tid < 4) yrbuf[tid] = (__bf16)0.0f;   // zero front pad

    // ---- dead-q rows: zero once; stage B skips them every chunk ----
    if (qDead) {
        bf16x4 z;
        z[0] = (__bf16)0.0f; z[1] = (__bf16)0.0f; z[2] = (__bf16)0.0f; z[3] = (__bf16)0.0f;
#pragma unroll
        for (int kk = 0; kk < 9; ++kk) {
            *(bf16x4*)(pqRow + kk * 32 + cB)     = z;
            *(bf16x4*)(pqRow + kk * 32 + cB + 4) = z;
        }
    }

    for (int chunk = 0; chunk < 4; ++chunk) {
        const int c0 = chunk * 32;

        // ---- stage A: load 4 x-rows x 16 cols, row-interp, write yr[piA] ----
        {
            const float* xp = x + ((size_t)(b * CC + c0 + cA) * HH) * WW;
            float4 v[4][4];   // [row][col4]
#pragma unroll
            for (int r = 0; r < 4; ++r) {
                if (rvA[r]) {
                    const float* rp = xp + (size_t)hrA[r] * WW + cg0;
#pragma unroll
                    for (int g = 0; g < 4; ++g) v[r][g] = *(const float4*)(rp + g * 4);
                } else {
#pragma unroll
                    for (int g = 0; g < 4; ++g) { v[r][g].x = 0.f; v[r][g].y = 0.f; v[r][g].z = 0.f; v[r][g].w = 0.f; }
                }
            }
            __bf16* yw = yrA + cA * YSTR + cg0;
#pragma unroll
            for (int kh = 0; kh < 3; ++kh) {
#pragma unroll
                for (int g = 0; g < 4; ++g) {
                    bf16x4 t;
                    t[0] = (__bf16)(v[kh][g].x + fhA * (v[kh + 1][g].x - v[kh][g].x));
                    t[1] = (__bf16)(v[kh][g].y + fhA * (v[kh + 1][g].y - v[kh][g].y));
                    t[2] = (__bf16)(v[kh][g].z + fhA * (v[kh + 1][g].z - v[kh][g].z));
                    t[3] = (__bf16)(v[kh][g].w + fhA * (v[kh + 1][g].w - v[kh][g].w));
                    *(bf16x4*)(yw + kh * 64 + g * 4) = t;
                }
            }
        }
        __syncthreads();   // barA: yr ready; prev chunk's pT MFMA-reads drained

        // ---- stage B: col-interp yr -> pT; reads hoisted for MLP ----
        if (!qDead) {
#pragma unroll
            for (int g = 0; g < 2; ++g) {
                const int cc0 = cB + g * 4;
                // issue ALL 24 b64 reads of this group before consuming:
                // 24 outstanding loads self-cover LDS latency at low occupancy
                bf16x4 rlo[12], rhi[12];
#pragma unroll
                for (int ci = 0; ci < 4; ++ci)
#pragma unroll
                    for (int kh = 0; kh < 3; ++kh) {
                        const __bf16* yc = yrB + (cc0 + ci) * YSTR + kh * 64 + wba;
                        rlo[ci * 3 + kh] = *(const bf16x4*)yc;
                        rhi[ci * 3 + kh] = *(const bf16x4*)(yc + 4);
                    }
                float tv[3][3][4];   // [kh][kw][ci]
#pragma unroll
                for (int ci = 0; ci < 4; ++ci)
#pragma unroll
                    for (int kh = 0; kh < 3; ++kh) {
                        bf16x4 a  = rlo[ci * 3 + kh];
                        bf16x4 bq = rhi[ci * 3 + kh];
                        float v0 = (float)a[0], v1 = (float)a[1], v2 = (float)a[2], v3 = (float)a[3];
                        float v4 = (float)bq[0], v5 = (float)bq[1], v6 = (float)bq[2];
                        float s0 = g1 ? v1 : v0; s0 = g2 ? v2 : s0; s0 = g3 ? v3 : s0;
                        float s1 = g1 ? v2 : v1; s1 = g2 ? v3 : s1; s1 = g3 ? v4 : s1;
                        float s2 = g1 ? v3 : v2; s2 = g2 ? v4 : s2; s2 = g3 ? v5 : s2;
                        float s3 = g1 ? v4 : v3; s3 = g2 ? v5 : s3; s3 = g3 ? v6 : s3;
                        s0 = mv[0] ? s0 : 0.0f;
                        s1 = mv[1] ? s1 : 0.0f;
                        s2 = mv[2] ? s2 : 0.0f;
                        s3 = mv[3] ? s3 : 0.0f;
                        tv[kh][0][ci] = s0 + fw * (s1 - s0);
                        tv[kh][1][ci] = s1 + fw * (s2 - s1);
                        tv[kh][2][ci] = s2 + fw * (s3 - s2);
                    }
#pragma unroll
                for (int kh = 0; kh < 3; ++kh)
#pragma unroll
                    for (int kw = 0; kw < 3; ++kw) {
                        bf16x4 pr;
                        pr[0] = (__bf16)tv[kh][kw][0];
                        pr[1] = (__bf16)tv[kh][kw][1];
                        pr[2] = (__bf16)tv[kh][kw][2];
                        pr[3] = (__bf16)tv[kh][kw][3];
                        *(bf16x4*)(pqRow + (kh * 3 + kw) * 32 + cc0) = pr;
                    }
            }
        }
        __syncthreads();   // barB: pT ready; yr reads drained

        // ---- MFMA: 9 taps x (2 o-tiles x 8 n-tiles); A in-loop (2 loads/tap) ----
        __builtin_amdgcn_s_setprio(1);
#pragma unroll
        for (int k = 0; k < 9; ++k) {
            const __bf16* wp = wt + ((size_t)(o0 + lr) * 9 + k) * CC + c0 + lg * 8;
            bf16x8 a0 = *(const bf16x8*)(wp);
            bf16x8 a1 = *(const bf16x8*)(wp + (size_t)16 * 9 * CC);
            bf16x8 bfr[8];
#pragma unroll
            for (int nt = 0; nt < 8; ++nt)
                bfr[nt] = *(const bf16x8*)&pT[(nt * 16 + lr) * PSTR + k * 32 + lg * 8];
#pragma unroll
            for (int nt = 0; nt < 8; ++nt) {
                acc[0][nt] = __builtin_amdgcn_mfma_f32_16x16x32_bf16(a0, bfr[nt], acc[0][nt], 0, 0, 0);
                acc[1][nt] = __builtin_amdgcn_mfma_f32_16x16x32_bf16(a1, bfr[nt], acc[1][nt], 0, 0, 0);
            }
        }
        __builtin_amdgcn_s_setprio(0);
        // pT overwrite fenced by next barA; yr overwrite fenced by barB.
        // dead-q pT rows are never rewritten -> stay zero.
    }

    // ---- epilogue: + bias, store (C/D: col=lane&15, row=(lane>>4)*4+reg) ----
#pragma unroll
    for (int ot = 0; ot < 2; ++ot) {
#pragma unroll
        for (int r = 0; r < 4; ++r) {
            int o = o0 + ot * 16 + lg * 4 + r;
            float bv = bias[o];
#pragma unroll
            for (int nt = 0; nt < 8; ++nt) {
                int pi = nt >> 1;
                int qc = (nt & 1) * 16 + lr;
                out[(((size_t)b * OO + o) * OHH + p0 + pi) * OWW + qc] = acc[ot][nt][r] + bv;
            }
        }
    }
}

// ---- fp32 fallback (no workspace) ----
__global__ __launch_bounds__(256)
void conv_fallback_kernel(const float* __restrict__ x, const float* __restrict__ w,
                          const float* __restrict__ bias, const float* __restrict__ shp,
                          const float* __restrict__ swp, float* __restrict__ out) {
    __shared__ __align__(16) float xr[4][WW];
    __shared__ __align__(16) float patch[9][OWW];
    const int tid = threadIdx.x;
    const int p = blockIdx.y;
    const int b = blockIdx.x;
    const float sh = shp[0];
    const float sw = swp[0];
    const float hpos = (float)p * sh - 1.0f;
    const float hbf  = floorf(hpos);
    const float fh   = hpos - hbf;
    const int   hb   = (int)hbf;
    const int og = tid & 63;
    const int qg = tid >> 6;
    const int o0 = og * 4;
    const int q0 = qg * 8;
    const int rr   = tid >> 6;
    const int colc = tid & 63;
    const int rowg = hb + rr;
    const bool rv = (rowg >= 0) && (rowg < HH);
    float acc[4][8];
#pragma unroll
    for (int i = 0; i < 4; ++i)
#pragma unroll
        for (int j = 0; j < 8; ++j) acc[i][j] = 0.0f;
    for (int c = 0; c < CC; ++c) {
        float vv = 0.0f;
        if (rv) vv = x[(((size_t)b * CC + c) * HH + rowg) * WW + colc];
        xr[rr][colc] = vv;
        __syncthreads();
        for (int it = tid; it < 9 * OWW; it += 256) {
            int k = it >> 5; int q = it & 31;
            int kh = k / 3;  int kw = k - kh * 3;
            float wpos = (float)q * sw - 1.0f + (float)kw;
            float wbf = floorf(wpos);
            float fwl = wpos - wbf;
            int wb = (int)wbf;
            float x00 = 0, x01 = 0, x10 = 0, x11 = 0;
            if (wb >= 0 && wb < WW)         { x00 = xr[kh][wb];     x10 = xr[kh + 1][wb]; }
            if (wb + 1 >= 0 && wb + 1 < WW) { x01 = xr[kh][wb + 1]; x11 = xr[kh + 1][wb + 1]; }
            float top = x00 * (1.0f - fwl) + x01 * fwl;
            float bot = x10 * (1.0f - fwl) + x11 * fwl;
            patch[k][q] = top * (1.0f - fh) + bot * fh;
        }
        __syncthreads();
        const float4* pv = (const float4*)&patch[0][0];
#pragma unroll
        for (int k = 0; k < 9; ++k) {
            const float* wb_ = w + (size_t)o0 * (CC * 9) + c * 9 + k;
            float wvv[4] = {wb_[0], wb_[1 * CC * 9], wb_[2 * CC * 9], wb_[3 * CC * 9]};
            float4 pa = pv[k * 8 + (q0 >> 2)];
            float4 pb = pv[k * 8 + (q0 >> 2) + 1];
#pragma unroll
            for (int oo2 = 0; oo2 < 4; ++oo2) {
                acc[oo2][0] += wvv[oo2] * pa.x; acc[oo2][1] += wvv[oo2] * pa.y;
                acc[oo2][2] += wvv[oo2] * pa.z; acc[oo2][3] += wvv[oo2] * pa.w;
                acc[oo2][4] += wvv[oo2] * pb.x; acc[oo2][5] += wvv[oo2] * pb.y;
                acc[oo2][6] += wvv[oo2] * pb.z; acc[oo2][7] += wvv[oo2] * pb.w;
            }
        }
    }
    float4 bv = ((const float4*)bias)[og];
    float bvv[4] = {bv.x, bv.y, bv.z, bv.w};
#pragma unroll
    for (int oo2 = 0; oo2 < 4; ++oo2) {
        size_t off = (((size_t)b * OO + o0 + oo2) * OHH + p) * OWW + q0;
        float4 r0, r1;
        r0.x = acc[oo2][0] + bvv[oo2]; r0.y = acc[oo2][1] + bvv[oo2];
        r0.z = acc[oo2][2] + bvv[oo2]; r0.w = acc[oo2][3] + bvv[oo2];
        r1.x = acc[oo2][4] + bvv[oo2]; r1.y = acc[oo2][5] + bvv[oo2];
        r1.z = acc[oo2][6] + bvv[oo2]; r1.w = acc[oo2][7] + bvv[oo2];
        *(float4*)(out + off)     = r0;
        *(float4*)(out + off + 4) = r1;
    }
}

extern "C" void kernel_launch(void* const* d_in, const int* in_sizes, int n_in,
                              void* d_out, int out_size, void* d_ws, size_t ws_size,
                              hipStream_t stream) {
    const float* x    = (const float*)d_in[0];
    const float* w    = (const float*)d_in[1];
    const float* bias = (const float*)d_in[2];
    const float* shp  = (const float*)d_in[3];
    const float* swp  = (const float*)d_in[4];
    float* out = (float*)d_out;

    const size_t wt_bytes = (size_t)OO * 9 * CC * sizeof(__bf16);   // 576 KB
    if (ws_size >= wt_bytes) {
        __bf16* wtp = (__bf16*)d_ws;
        int n = OO * 9 * CC;
        wtrans_bf16_kernel<<<(n + 255) / 256, 256, 0, stream>>>(w, wtp);
        dim3 grid(BB, OHH / 4);
        conv_mfma_kernel<<<grid, 512, 0, stream>>>(x, wtp, bias, shp, swp, out);
    } else {
        dim3 grid(BB, OHH);
        conv_fallback_kernel<<<grid, 256, 0, stream>>>(x, w, bias, shp, swp, out);
    }
}